// Round 21
// baseline (395.668 us; speedup 1.0000x reference)
//
#include <hip/hip_runtime.h>
#include <stdint.h>

#define Bb    4
#define EMBED 96
#define NCH   3
#define Hh    512
#define Ww    512
#define HWSZ  (Hh * Ww)
#define KN    49152      // K*N oversampled points
#define NPT   16384      // N final points
#define NIMP  12288      // importance points
#define NCOV  4096       // coverage points
#define SORTN 65536      // KN padded to power of two
#define STILE 8192       // bitonic LDS tile (64 KiB of u64)

// Opaque register fence (R18 CORRECTNESS-CRITICAL): hipcc -ffp-contract=fast
// otherwise fuses mul+add into fma and the selection ranking diverges from
// the numpy reference at ulp level.
__device__ __forceinline__ float opaque(float v) {
    asm volatile("" : "+v"(v));
    return v;
}

// ---------- coords (all ops EXACT for grid-aligned p; no fence needed) ----------
__device__ __forceinline__ void ref_coords(float p, int& i0, float& w0, float& w1) {
    float g  = 2.0f * p - 1.0f;
    float t  = (g + 1.0f) * 512.0f - 1.0f;
    float ix = t * 0.5f;
    float f  = floorf(ix);
    i0 = (int)f;
    w1 = ix - f;
    w0 = 1.0f - w1;
}

__device__ __forceinline__ uint32_t sortable_desc32(float v) {
    uint32_t u = __float_as_uint(v);
    uint32_t asc = (u >> 31) ? ~u : (u ^ 0x80000000u);
    return ~asc;
}

__device__ __forceinline__ uint32_t part1by1(uint32_t v) {
    v &= 0xFFFFu;
    v = (v | (v << 8)) & 0x00FF00FFu;
    v = (v | (v << 4)) & 0x0F0F0F0Fu;
    v = (v | (v << 2)) & 0x33333333u;
    v = (v | (v << 1)) & 0x55555555u;
    return v;
}

// ---------- kernel 0: per-pixel (max, median) of squared diffs -> float2 map ----------
__global__ void build_maps(const float* __restrict__ res,
                           const float* __restrict__ outm,
                           float2* __restrict__ maps) {
    int lb  = blockIdx.y;
    int pix = blockIdx.x * blockDim.x + threadIdx.x;   // < HWSZ
    const float* r0 = res  + (size_t)lb * NCH * HWSZ;
    const float* o0 = outm + (size_t)lb * NCH * HWSZ;
    float d0 = opaque(o0[pix]            - r0[pix]);
    float d1 = opaque(o0[HWSZ + pix]     - r0[HWSZ + pix]);
    float d2 = opaque(o0[2 * HWSZ + pix] - r0[2 * HWSZ + pix]);
    float a  = opaque(d0 * d0);
    float bq = opaque(d1 * d1);
    float c  = opaque(d2 * d2);
    float m0 = fmaxf(fmaxf(a, bq), c);                        // max
    float m1 = fmaxf(fminf(a, bq), fminf(fmaxf(a, bq), c));   // median
    maps[(size_t)lb * HWSZ + pix] = make_float2(m0, m1);
}

// ---------- kernel 1a: fenced strict-f32 uncertainty via maps -> u64 sort keys ----------
__global__ void uncert_keys_maps(const float2* __restrict__ maps,
                                 const float* __restrict__ over_gen,
                                 uint64_t* __restrict__ keys) {
    int lb = blockIdx.y;
    int i  = blockIdx.x * blockDim.x + threadIdx.x;   // < SORTN
    if (i >= KN) { keys[(size_t)lb * SORTN + i] = 0xFFFFFFFFFFFFFFFFull; return; }

    float px = over_gen[((size_t)lb * KN + i) * 2 + 0];
    float py = over_gen[((size_t)lb * KN + i) * 2 + 1];
    int x0, y0;
    float wx0, wx1, wy0, wy1;
    ref_coords(px, x0, wx0, wx1);
    ref_coords(py, y0, wy0, wy1);

    const float2* mp = maps + (size_t)lb * HWSZ;
    int   cxs[4] = {x0, x0 + 1, x0, x0 + 1};
    int   cys[4] = {y0, y0, y0 + 1, y0 + 1};
    float wxs[4] = {wx0, wx1, wx0, wx1};
    float wys[4] = {wy0, wy0, wy1, wy1};

    float acc0 = 0.0f, acc1 = 0.0f;
#pragma unroll
    for (int q = 0; q < 4; ++q) {
        int xq = cxs[q], yq = cys[q];
        if (xq < 0 || xq >= Ww || yq < 0 || yq >= Hh) continue;   // zero term
        float2 m = mp[yq * Ww + xq];
        float wq = opaque(wxs[q] * wys[q]);
        float t0 = opaque(wq * m.x);
        float t1 = opaque(wq * m.y);
        acc0 = opaque(acc0 + t0);
        acc1 = opaque(acc1 + t1);
    }
    float u = opaque(acc1 - acc0);
    keys[(size_t)lb * SORTN + i] =
        ((uint64_t)sortable_desc32(u) << 32) | (uint32_t)i;
}

// ---------- kernel 1b: direct variant (fallback when ws can't hold maps) ----------
__global__ void uncert_keys_direct(const float* __restrict__ res,
                                   const float* __restrict__ outm,
                                   const float* __restrict__ over_gen,
                                   uint64_t* __restrict__ keys) {
    int lb = blockIdx.y;
    int i  = blockIdx.x * blockDim.x + threadIdx.x;
    if (i >= KN) { keys[(size_t)lb * SORTN + i] = 0xFFFFFFFFFFFFFFFFull; return; }

    float px = over_gen[((size_t)lb * KN + i) * 2 + 0];
    float py = over_gen[((size_t)lb * KN + i) * 2 + 1];
    int x0, y0;
    float wx0, wx1, wy0, wy1;
    ref_coords(px, x0, wx0, wx1);
    ref_coords(py, y0, wy0, wy1);

    const float* r0 = res  + (size_t)lb * NCH * HWSZ;
    const float* o0 = outm + (size_t)lb * NCH * HWSZ;
    int   cxs[4] = {x0, x0 + 1, x0, x0 + 1};
    int   cys[4] = {y0, y0, y0 + 1, y0 + 1};
    float wxs[4] = {wx0, wx1, wx0, wx1};
    float wys[4] = {wy0, wy0, wy1, wy1};

    float acc0 = 0.0f, acc1 = 0.0f;
#pragma unroll
    for (int q = 0; q < 4; ++q) {
        int xq = cxs[q], yq = cys[q];
        if (xq < 0 || xq >= Ww || yq < 0 || yq >= Hh) continue;
        int off = yq * Ww + xq;
        float d0 = opaque(o0[off]            - r0[off]);
        float d1 = opaque(o0[HWSZ + off]     - r0[HWSZ + off]);
        float d2 = opaque(o0[2 * HWSZ + off] - r0[2 * HWSZ + off]);
        float a  = opaque(d0 * d0);
        float bq = opaque(d1 * d1);
        float c  = opaque(d2 * d2);
        float m0 = fmaxf(fmaxf(a, bq), c);
        float m1 = fmaxf(fminf(a, bq), fminf(fmaxf(a, bq), c));
        float wq = opaque(wxs[q] * wys[q]);
        float t0 = opaque(wq * m0);
        float t1 = opaque(wq * m1);
        acc0 = opaque(acc0 + t0);
        acc1 = opaque(acc1 + t1);
    }
    float u = opaque(acc1 - acc0);
    keys[(size_t)lb * SORTN + i] =
        ((uint64_t)sortable_desc32(u) << 32) | (uint32_t)i;
}

// ---------- bitonic sort, 8192-element LDS tiles (1024 thr × 8 elems) ----------
// fused local: stages k = 2..8192 entirely in LDS
__global__ void __launch_bounds__(1024) bl_first(uint64_t* __restrict__ keys,
                                                 int tile_mask) {
    __shared__ uint64_t sh[STILE];
    uint64_t* base = keys + (size_t)blockIdx.x * STILE;
    int t = threadIdx.x;
#pragma unroll
    for (int e = 0; e < 8; ++e) sh[t + e * 1024] = base[t + e * 1024];
    __syncthreads();
    int gbase = (blockIdx.x & tile_mask) * STILE;
    for (int k = 2; k <= STILE; k <<= 1) {
        for (int j = k >> 1; j >= 1; j >>= 1) {
#pragma unroll
            for (int e = 0; e < 4; ++e) {
                int tt = t + e * 1024;          // CE index 0..4095
                int low = tt & (j - 1);
                int i = ((tt ^ low) << 1) | low;
                int l = i | j;
                bool up = (((gbase + i) & k) == 0);
                uint64_t a = sh[i], c = sh[l];
                if ((a > c) == up) { sh[i] = c; sh[l] = a; }
            }
            __syncthreads();
        }
    }
#pragma unroll
    for (int e = 0; e < 8; ++e) base[t + e * 1024] = sh[t + e * 1024];
}

// one global compare-exchange pass (stride j >= STILE) of stage k
__global__ void bitonic_global_g(uint64_t* __restrict__ keys, int j, int k, int pbits) {
    int t = blockIdx.x * blockDim.x + threadIdx.x;
    int b = t >> pbits;
    int p = t & ((1 << pbits) - 1);
    int low = p & (j - 1);
    int i = ((p ^ low) << 1) | low;
    int l = i | j;
    bool up = ((i & k) == 0);
    uint64_t* kb = keys + ((size_t)b << (pbits + 1));
    uint64_t a = kb[i], c = kb[l];
    if ((a > c) == up) { kb[i] = c; kb[l] = a; }
}

// fused local tail of stage k (k >= 2*STILE): strides STILE/2..1, direction const/tile
__global__ void __launch_bounds__(1024) bl_k(uint64_t* __restrict__ keys,
                                             int k, int tile_mask) {
    __shared__ uint64_t sh[STILE];
    uint64_t* base = keys + (size_t)blockIdx.x * STILE;
    int t = threadIdx.x;
#pragma unroll
    for (int e = 0; e < 8; ++e) sh[t + e * 1024] = base[t + e * 1024];
    __syncthreads();
    int gbase = (blockIdx.x & tile_mask) * STILE;
    bool up = ((gbase & k) == 0);
    for (int j = STILE / 2; j >= 1; j >>= 1) {
#pragma unroll
        for (int e = 0; e < 4; ++e) {
            int tt = t + e * 1024;
            int low = tt & (j - 1);
            int i = ((tt ^ low) << 1) | low;
            int l = i | j;
            uint64_t a = sh[i], c = sh[l];
            if ((a > c) == up) { sh[i] = c; sh[l] = a; }
        }
        __syncthreads();
    }
#pragma unroll
    for (int e = 0; e < 8; ++e) base[t + e * 1024] = sh[t + e * 1024];
}

static void run_sort(uint64_t* keys, int nb, int seg, hipStream_t stream) {
    int tiles = seg / STILE;
    int tile_mask = tiles - 1;
    int pbits = 31 - __builtin_clz((unsigned)(seg >> 1));
    bl_first<<<nb * tiles, 1024, 0, stream>>>(keys, tile_mask);
    for (int k = STILE * 2; k <= seg; k <<= 1) {
        for (int j = k >> 1; j >= STILE; j >>= 1)
            bitonic_global_g<<<nb * (seg / 2) / 256, 256, 0, stream>>>(keys, j, k, pbits);
        bl_k<<<nb * tiles, 1024, 0, stream>>>(keys, k, tile_mask);
    }
}

// ---------- kernel 2: per-point Morton spatial keys for render reorder ----------
__global__ void pkey_kernel(const uint64_t* __restrict__ keys,
                            const float* __restrict__ over_gen,
                            const float* __restrict__ coverage,
                            uint64_t* __restrict__ pkeys) {
    int lb = blockIdx.y;
    int n  = blockIdx.x * blockDim.x + threadIdx.x;   // < NPT
    float px, py;
    if (n < NIMP) {
        uint32_t idx = (uint32_t)keys[((size_t)lb << 16) + n];
        if (idx >= KN) idx = 0;
        px = over_gen[((size_t)lb * KN + idx) * 2 + 0];
        py = over_gen[((size_t)lb * KN + idx) * 2 + 1];
    } else {
        int m = n - NIMP;
        px = coverage[((size_t)lb * NCOV + m) * 2 + 0];
        py = coverage[((size_t)lb * NCOV + m) * 2 + 1];
    }
    int x0, y0;
    float w0, w1;
    ref_coords(px, x0, w0, w1);
    int xi = x0;
    ref_coords(py, y0, w0, w1);
    int yi = y0;
    xi = min(max(xi, 0), Ww - 1);
    yi = min(max(yi, 0), Hh - 1);
    uint32_t morton = part1by1((uint32_t)xi) | (part1by1((uint32_t)yi) << 1);
    pkeys[(size_t)lb * NPT + n] = ((uint64_t)morton << 32) | (uint32_t)n;
}

// ---------- kernel 3: render (optionally via Morton-sorted point order) ----------
__global__ void render_kernel(const float* __restrict__ x,
                              const float* __restrict__ outm,
                              const float* __restrict__ w_mlp,
                              const float* __restrict__ over_gen,
                              const float* __restrict__ coverage,
                              const uint64_t* __restrict__ keys,
                              const uint64_t* __restrict__ pkeys,  // may be null
                              float* __restrict__ dst) {
    int gid = blockIdx.x * blockDim.x + threadIdx.x;
    int pt = gid >> 3, r = gid & 7;
    int lb = blockIdx.y;
    int n = pt;                                  // output slot
    if (pkeys) n = (uint32_t)pkeys[(size_t)lb * NPT + pt];   // sorted order

    float px, py;
    if (n < NIMP) {
        uint32_t idx = (uint32_t)keys[((size_t)lb << 16) + n];
        if (idx >= KN) idx = 0;
        px = over_gen[((size_t)lb * KN + idx) * 2 + 0];
        py = over_gen[((size_t)lb * KN + idx) * 2 + 1];
    } else {
        int m = n - NIMP;
        px = coverage[((size_t)lb * NCOV + m) * 2 + 0];
        py = coverage[((size_t)lb * NCOV + m) * 2 + 1];
    }

    int x0, y0;
    float wx0, wx1, wy0, wy1;
    ref_coords(px, x0, wx0, wx1);
    ref_coords(py, y0, wy0, wy1);

    int   cxs[4] = {x0, x0 + 1, x0, x0 + 1};
    int   cys[4] = {y0, y0, y0 + 1, y0 + 1};
    float wcs[4] = {wx0 * wy0, wx1 * wy0, wx0 * wy1, wx1 * wy1};
    bool  vld[4];
#pragma unroll
    for (int q = 0; q < 4; ++q)
        vld[q] = (cxs[q] >= 0) & (cxs[q] < Ww) & (cys[q] >= 0) & (cys[q] < Hh);

    float acc0 = 0.0f, acc1 = 0.0f, acc2 = 0.0f;
    for (int c = r; c < NCH + EMBED; c += 8) {
        const float* src = (c < NCH)
            ? (outm + ((size_t)lb * NCH + c) * HWSZ)
            : (x + ((size_t)lb * EMBED + (c - NCH)) * HWSZ);
        float f = 0.0f;
#pragma unroll
        for (int q = 0; q < 4; ++q) {
            if (vld[q]) f += wcs[q] * src[cys[q] * Ww + cxs[q]];
        }
        acc0 += w_mlp[c] * f;
        acc1 += w_mlp[99 + c] * f;
        acc2 += w_mlp[198 + c] * f;
    }
#pragma unroll
    for (int d = 1; d < 8; d <<= 1) {
        acc0 += __shfl_xor(acc0, d);
        acc1 += __shfl_xor(acc1, d);
        acc2 += __shfl_xor(acc2, d);
    }
    if (r == 0) {
        size_t ob = (size_t)lb * 3 * NPT + n;
        dst[ob]           = fmaxf(acc0, 0.0f);
        dst[ob + NPT]     = fmaxf(acc1, 0.0f);
        dst[ob + 2 * NPT] = fmaxf(acc2, 0.0f);
    }
}

extern "C" void kernel_launch(void* const* d_in, const int* in_sizes, int n_in,
                              void* d_out, int out_size, void* d_ws, size_t ws_size,
                              hipStream_t stream) {
    const float* x        = (const float*)d_in[0];
    const float* res      = (const float*)d_in[1];
    const float* outm     = (const float*)d_in[2];
    const float* w_mlp    = (const float*)d_in[3];
    const float* over_gen = (const float*)d_in[4];
    const float* coverage = (const float*)d_in[5];
    float* dst = (float*)d_out;

    const size_t keys_sz = (size_t)Bb * SORTN * sizeof(uint64_t);   // 2 MiB
    const size_t pkey_sz = (size_t)Bb * NPT * sizeof(uint64_t);     // 512 KiB
    const size_t maps_sz = (size_t)Bb * HWSZ * sizeof(float2);      // 8 MiB

    uint64_t* keys = (uint64_t*)d_ws;
    dim3 gU(SORTN / 256, Bb), gP(NPT / 256, Bb), gD(NPT * 8 / 256, Bb);

    if (ws_size >= keys_sz + pkey_sz + maps_sz) {
        uint64_t* pkeys = (uint64_t*)((char*)d_ws + keys_sz);
        float2*   maps  = (float2*)((char*)d_ws + keys_sz + pkey_sz);
        dim3 gM(HWSZ / 256, Bb);
        build_maps<<<gM, 256, 0, stream>>>(res, outm, maps);
        uncert_keys_maps<<<gU, 256, 0, stream>>>(maps, over_gen, keys);
        run_sort(keys, Bb, SORTN, stream);
        pkey_kernel<<<gP, 256, 0, stream>>>(keys, over_gen, coverage, pkeys);
        run_sort(pkeys, Bb, NPT, stream);
        render_kernel<<<gD, 256, 0, stream>>>(x, outm, w_mlp, over_gen, coverage,
                                              keys, pkeys, dst);
    } else if (ws_size >= keys_sz + pkey_sz) {
        uint64_t* pkeys = (uint64_t*)((char*)d_ws + keys_sz);
        uncert_keys_direct<<<gU, 256, 0, stream>>>(res, outm, over_gen, keys);
        run_sort(keys, Bb, SORTN, stream);
        pkey_kernel<<<gP, 256, 0, stream>>>(keys, over_gen, coverage, pkeys);
        run_sort(pkeys, Bb, NPT, stream);
        render_kernel<<<gD, 256, 0, stream>>>(x, outm, w_mlp, over_gen, coverage,
                                              keys, pkeys, dst);
    } else {
        // minimal tier
        uncert_keys_direct<<<gU, 256, 0, stream>>>(res, outm, over_gen, keys);
        run_sort(keys, Bb, SORTN, stream);
        render_kernel<<<gD, 256, 0, stream>>>(x, outm, w_mlp, over_gen, coverage,
                                              keys, (const uint64_t*)nullptr, dst);
    }
}

// Round 22
// 283.726 us; speedup vs baseline: 1.3945x; 1.3945x over previous
//
#include <hip/hip_runtime.h>
#include <stdint.h>

#define Bb    4
#define EMBED 96
#define NCH   3
#define Hh    512
#define Ww    512
#define HWSZ  (Hh * Ww)
#define KN    49152      // K*N oversampled points
#define NPT   16384      // N final points
#define NIMP  12288      // importance points
#define NCOV  4096       // coverage points
#define SORTN 65536      // KN padded to power of two
#define NBUCK 1024       // counting-sort buckets (top-10 Morton bits)

// Opaque register fence (R18 CORRECTNESS-CRITICAL): hipcc -ffp-contract=fast
// otherwise fuses mul+add into fma and the selection ranking diverges from
// the numpy reference at ulp level.
__device__ __forceinline__ float opaque(float v) {
    asm volatile("" : "+v"(v));
    return v;
}

// ---------- coords (all ops EXACT for grid-aligned p; no fence needed) ----------
__device__ __forceinline__ void ref_coords(float p, int& i0, float& w0, float& w1) {
    float g  = 2.0f * p - 1.0f;
    float t  = (g + 1.0f) * 512.0f - 1.0f;
    float ix = t * 0.5f;
    float f  = floorf(ix);
    i0 = (int)f;
    w1 = ix - f;
    w0 = 1.0f - w1;
}

__device__ __forceinline__ uint32_t sortable_desc32(float v) {
    uint32_t u = __float_as_uint(v);
    uint32_t asc = (u >> 31) ? ~u : (u ^ 0x80000000u);
    return ~asc;
}

__device__ __forceinline__ uint32_t part1by1(uint32_t v) {
    v &= 0xFFFFu;
    v = (v | (v << 8)) & 0x00FF00FFu;
    v = (v | (v << 4)) & 0x0F0F0F0Fu;
    v = (v | (v << 2)) & 0x33333333u;
    v = (v | (v << 1)) & 0x55555555u;
    return v;
}

// ---------- kernel 0: per-pixel (max, median) of squared diffs -> float2 map ----------
__global__ void build_maps(const float* __restrict__ res,
                           const float* __restrict__ outm,
                           float2* __restrict__ maps) {
    int lb  = blockIdx.y;
    int pix = blockIdx.x * blockDim.x + threadIdx.x;   // < HWSZ
    const float* r0 = res  + (size_t)lb * NCH * HWSZ;
    const float* o0 = outm + (size_t)lb * NCH * HWSZ;
    float d0 = opaque(o0[pix]            - r0[pix]);
    float d1 = opaque(o0[HWSZ + pix]     - r0[HWSZ + pix]);
    float d2 = opaque(o0[2 * HWSZ + pix] - r0[2 * HWSZ + pix]);
    float a  = opaque(d0 * d0);
    float bq = opaque(d1 * d1);
    float c  = opaque(d2 * d2);
    float m0 = fmaxf(fmaxf(a, bq), c);                        // max
    float m1 = fmaxf(fminf(a, bq), fminf(fmaxf(a, bq), c));   // median
    maps[(size_t)lb * HWSZ + pix] = make_float2(m0, m1);
}

// ---------- kernel 1a: fenced strict-f32 uncertainty via maps -> u64 sort keys ----------
__global__ void uncert_keys_maps(const float2* __restrict__ maps,
                                 const float* __restrict__ over_gen,
                                 uint64_t* __restrict__ keys) {
    int lb = blockIdx.y;
    int i  = blockIdx.x * blockDim.x + threadIdx.x;   // < SORTN
    if (i >= KN) { keys[(size_t)lb * SORTN + i] = 0xFFFFFFFFFFFFFFFFull; return; }

    float px = over_gen[((size_t)lb * KN + i) * 2 + 0];
    float py = over_gen[((size_t)lb * KN + i) * 2 + 1];
    int x0, y0;
    float wx0, wx1, wy0, wy1;
    ref_coords(px, x0, wx0, wx1);
    ref_coords(py, y0, wy0, wy1);

    const float2* mp = maps + (size_t)lb * HWSZ;
    int   cxs[4] = {x0, x0 + 1, x0, x0 + 1};
    int   cys[4] = {y0, y0, y0 + 1, y0 + 1};
    float wxs[4] = {wx0, wx1, wx0, wx1};
    float wys[4] = {wy0, wy0, wy1, wy1};

    float acc0 = 0.0f, acc1 = 0.0f;
#pragma unroll
    for (int q = 0; q < 4; ++q) {
        int xq = cxs[q], yq = cys[q];
        if (xq < 0 || xq >= Ww || yq < 0 || yq >= Hh) continue;   // zero term
        float2 m = mp[yq * Ww + xq];
        float wq = opaque(wxs[q] * wys[q]);
        float t0 = opaque(wq * m.x);
        float t1 = opaque(wq * m.y);
        acc0 = opaque(acc0 + t0);
        acc1 = opaque(acc1 + t1);
    }
    float u = opaque(acc1 - acc0);
    keys[(size_t)lb * SORTN + i] =
        ((uint64_t)sortable_desc32(u) << 32) | (uint32_t)i;
}

// ---------- kernel 1b: direct variant (fallback when ws can't hold maps) ----------
__global__ void uncert_keys_direct(const float* __restrict__ res,
                                   const float* __restrict__ outm,
                                   const float* __restrict__ over_gen,
                                   uint64_t* __restrict__ keys) {
    int lb = blockIdx.y;
    int i  = blockIdx.x * blockDim.x + threadIdx.x;
    if (i >= KN) { keys[(size_t)lb * SORTN + i] = 0xFFFFFFFFFFFFFFFFull; return; }

    float px = over_gen[((size_t)lb * KN + i) * 2 + 0];
    float py = over_gen[((size_t)lb * KN + i) * 2 + 1];
    int x0, y0;
    float wx0, wx1, wy0, wy1;
    ref_coords(px, x0, wx0, wx1);
    ref_coords(py, y0, wy0, wy1);

    const float* r0 = res  + (size_t)lb * NCH * HWSZ;
    const float* o0 = outm + (size_t)lb * NCH * HWSZ;
    int   cxs[4] = {x0, x0 + 1, x0, x0 + 1};
    int   cys[4] = {y0, y0, y0 + 1, y0 + 1};
    float wxs[4] = {wx0, wx1, wx0, wx1};
    float wys[4] = {wy0, wy0, wy1, wy1};

    float acc0 = 0.0f, acc1 = 0.0f;
#pragma unroll
    for (int q = 0; q < 4; ++q) {
        int xq = cxs[q], yq = cys[q];
        if (xq < 0 || xq >= Ww || yq < 0 || yq >= Hh) continue;
        int off = yq * Ww + xq;
        float d0 = opaque(o0[off]            - r0[off]);
        float d1 = opaque(o0[HWSZ + off]     - r0[HWSZ + off]);
        float d2 = opaque(o0[2 * HWSZ + off] - r0[2 * HWSZ + off]);
        float a  = opaque(d0 * d0);
        float bq = opaque(d1 * d1);
        float c  = opaque(d2 * d2);
        float m0 = fmaxf(fmaxf(a, bq), c);
        float m1 = fmaxf(fminf(a, bq), fminf(fmaxf(a, bq), c));
        float wq = opaque(wxs[q] * wys[q]);
        float t0 = opaque(wq * m0);
        float t1 = opaque(wq * m1);
        acc0 = opaque(acc0 + t0);
        acc1 = opaque(acc1 + t1);
    }
    float u = opaque(acc1 - acc0);
    keys[(size_t)lb * SORTN + i] =
        ((uint64_t)sortable_desc32(u) << 32) | (uint32_t)i;
}

// ---------- bitonic sort, 2048-elem LDS tiles (R20-proven locals) ----------
// fused local: stages k = 2..2048 entirely in LDS. grid.x = nb*32 tiles.
__global__ void __launch_bounds__(1024) bitonic_local_first(uint64_t* __restrict__ keys) {
    __shared__ uint64_t sh[2048];
    uint64_t* base = keys + (size_t)blockIdx.x * 2048;
    int t = threadIdx.x;
    sh[t]        = base[t];
    sh[t + 1024] = base[t + 1024];
    __syncthreads();
    int gbase = (blockIdx.x & 31) << 11;
    for (int k = 2; k <= 2048; k <<= 1) {
        for (int j = k >> 1; j >= 1; j >>= 1) {
            int low = t & (j - 1);
            int i = ((t ^ low) << 1) | low;
            int l = i | j;
            bool up = (((gbase + i) & k) == 0);
            uint64_t a = sh[i], c = sh[l];
            if ((a > c) == up) { sh[i] = c; sh[l] = a; }
            __syncthreads();
        }
    }
    base[t]        = sh[t];
    base[t + 1024] = sh[t + 1024];
}

// FUSED global passes of stage k = 2^(11+m): strides j = k/2 .. 2048 in one
// kernel. Block gathers 2048 elements (GPB groups × GS=2^m elems, coalesced
// per e-slice) into LDS, runs the m-pass cascade, writes back. CE-identical
// to m separate global passes. grid = (32, nb).
__global__ void __launch_bounds__(1024) bitonic_global_fused(uint64_t* __restrict__ keys,
                                                             int m) {
    __shared__ uint64_t sh[2048];
    int lb  = blockIdx.y;
    int blk = blockIdx.x;            // 0..31
    int t   = threadIdx.x;
    int GS  = 1 << m;                // group size (2..32)
    int GPB = 2048 >> m;             // groups per block
    int gstart = blk * GPB;
    int esh = 11 - m;                // log2(GPB)
    uint64_t* base = keys + ((size_t)lb << 16);

    for (int s = t; s < 2048; s += 1024) {
        int e  = s >> esh;
        int gl = s & (GPB - 1);
        int g  = gstart + gl;
        int full = (g & 2047) | (e << 11) | ((g >> 11) << (11 + m));
        sh[s] = base[full];
    }
    __syncthreads();
    for (int jl = GS >> 1; jl >= 1; jl >>= 1) {
        int gl = t & (GPB - 1);
        int pe = t >> esh;           // 0..GS/2-1
        int low = pe & (jl - 1);
        int e0 = ((pe ^ low) << 1) | low;
        int e1 = e0 | jl;
        bool up = ((((gstart + gl) >> 11) & 1) == 0);  // bit log2(k) of full idx
        int s0 = e0 * GPB + gl, s1 = e1 * GPB + gl;
        uint64_t a = sh[s0], c = sh[s1];
        if ((a > c) == up) { sh[s0] = c; sh[s1] = a; }
        __syncthreads();
    }
    for (int s = t; s < 2048; s += 1024) {
        int e  = s >> esh;
        int gl = s & (GPB - 1);
        int g  = gstart + gl;
        int full = (g & 2047) | (e << 11) | ((g >> 11) << (11 + m));
        base[full] = sh[s];
    }
}

// fused local tail of stage k (k >= 4096): strides 1024..1, direction const/tile
__global__ void __launch_bounds__(1024) bitonic_local_k(uint64_t* __restrict__ keys, int k) {
    __shared__ uint64_t sh[2048];
    uint64_t* base = keys + (size_t)blockIdx.x * 2048;
    int t = threadIdx.x;
    sh[t]        = base[t];
    sh[t + 1024] = base[t + 1024];
    __syncthreads();
    int gbase = (blockIdx.x & 31) << 11;
    bool up = ((gbase & k) == 0);
    for (int j = 1024; j >= 1; j >>= 1) {
        int low = t & (j - 1);
        int i = ((t ^ low) << 1) | low;
        int l = i | j;
        uint64_t a = sh[i], c = sh[l];
        if ((a > c) == up) { sh[i] = c; sh[l] = a; }
        __syncthreads();
    }
    base[t]        = sh[t];
    base[t + 1024] = sh[t + 1024];
}

static void run_sort_big(uint64_t* keys, int nb, hipStream_t stream) {
    bitonic_local_first<<<nb * 32, 1024, 0, stream>>>(keys);
    for (int kbit = 12; kbit <= 16; ++kbit) {
        bitonic_global_fused<<<dim3(32, nb), 1024, 0, stream>>>(keys, kbit - 11);
        bitonic_local_k<<<nb * 32, 1024, 0, stream>>>(keys, 1 << kbit);
    }
}

// ---------- counting-sort point reorder (Morton top-10 bits) ----------
__global__ void hist_kernel(const uint64_t* __restrict__ keys,
                            const float* __restrict__ over_gen,
                            const float* __restrict__ coverage,
                            uint32_t* __restrict__ hist,
                            uint32_t* __restrict__ mort) {
    int lb = blockIdx.y;
    int n  = blockIdx.x * blockDim.x + threadIdx.x;   // < NPT
    float px, py;
    if (n < NIMP) {
        uint32_t idx = (uint32_t)keys[((size_t)lb << 16) + n];
        if (idx >= KN) idx = 0;
        px = over_gen[((size_t)lb * KN + idx) * 2 + 0];
        py = over_gen[((size_t)lb * KN + idx) * 2 + 1];
    } else {
        int m = n - NIMP;
        px = coverage[((size_t)lb * NCOV + m) * 2 + 0];
        py = coverage[((size_t)lb * NCOV + m) * 2 + 1];
    }
    int x0, y0;
    float w0, w1;
    ref_coords(px, x0, w0, w1);
    ref_coords(py, y0, w0, w1);
    int xi = min(max(x0, 0), Ww - 1);
    int yi = min(max(y0, 0), Hh - 1);
    uint32_t morton = part1by1((uint32_t)xi) | (part1by1((uint32_t)yi) << 1);  // 18 bits
    uint32_t bucket = morton >> 8;                                             // top 10
    mort[(size_t)lb * NPT + n] = bucket;
    atomicAdd(&hist[(size_t)lb * NBUCK + bucket], 1u);
}

__global__ void __launch_bounds__(1024) scan_kernel(const uint32_t* __restrict__ hist,
                                                    uint32_t* __restrict__ offs) {
    __shared__ uint32_t sh[NBUCK];
    int lb = blockIdx.x;
    int t  = threadIdx.x;
    uint32_t orig = hist[(size_t)lb * NBUCK + t];
    sh[t] = orig;
    __syncthreads();
    for (int d = 1; d < NBUCK; d <<= 1) {
        uint32_t add = (t >= d) ? sh[t - d] : 0u;
        __syncthreads();
        sh[t] += add;
        __syncthreads();
    }
    offs[(size_t)lb * NBUCK + t] = sh[t] - orig;   // exclusive prefix
}

__global__ void scatter_kernel(const uint32_t* __restrict__ mort,
                               uint32_t* __restrict__ offs,
                               uint32_t* __restrict__ porder) {
    int lb = blockIdx.y;
    int n  = blockIdx.x * blockDim.x + threadIdx.x;   // < NPT
    uint32_t b = mort[(size_t)lb * NPT + n];
    uint32_t pos = atomicAdd(&offs[(size_t)lb * NBUCK + b], 1u);
    porder[(size_t)lb * NPT + pos] = (uint32_t)n;
}

// ---------- kernel 3: render (optionally via bucketed point order) ----------
__global__ void render_kernel(const float* __restrict__ x,
                              const float* __restrict__ outm,
                              const float* __restrict__ w_mlp,
                              const float* __restrict__ over_gen,
                              const float* __restrict__ coverage,
                              const uint64_t* __restrict__ keys,
                              const uint32_t* __restrict__ porder,  // may be null
                              float* __restrict__ dst) {
    int gid = blockIdx.x * blockDim.x + threadIdx.x;
    int pt = gid >> 3, r = gid & 7;
    int lb = blockIdx.y;
    int n = pt;                                  // output slot
    if (porder) n = porder[(size_t)lb * NPT + pt];

    float px, py;
    if (n < NIMP) {
        uint32_t idx = (uint32_t)keys[((size_t)lb << 16) + n];
        if (idx >= KN) idx = 0;
        px = over_gen[((size_t)lb * KN + idx) * 2 + 0];
        py = over_gen[((size_t)lb * KN + idx) * 2 + 1];
    } else {
        int m = n - NIMP;
        px = coverage[((size_t)lb * NCOV + m) * 2 + 0];
        py = coverage[((size_t)lb * NCOV + m) * 2 + 1];
    }

    int x0, y0;
    float wx0, wx1, wy0, wy1;
    ref_coords(px, x0, wx0, wx1);
    ref_coords(py, y0, wy0, wy1);

    int   cxs[4] = {x0, x0 + 1, x0, x0 + 1};
    int   cys[4] = {y0, y0, y0 + 1, y0 + 1};
    float wcs[4] = {wx0 * wy0, wx1 * wy0, wx0 * wy1, wx1 * wy1};
    bool  vld[4];
#pragma unroll
    for (int q = 0; q < 4; ++q)
        vld[q] = (cxs[q] >= 0) & (cxs[q] < Ww) & (cys[q] >= 0) & (cys[q] < Hh);

    float acc0 = 0.0f, acc1 = 0.0f, acc2 = 0.0f;
    for (int c = r; c < NCH + EMBED; c += 8) {
        const float* src = (c < NCH)
            ? (outm + ((size_t)lb * NCH + c) * HWSZ)
            : (x + ((size_t)lb * EMBED + (c - NCH)) * HWSZ);
        float f = 0.0f;
#pragma unroll
        for (int q = 0; q < 4; ++q) {
            if (vld[q]) f += wcs[q] * src[cys[q] * Ww + cxs[q]];
        }
        acc0 += w_mlp[c] * f;
        acc1 += w_mlp[99 + c] * f;
        acc2 += w_mlp[198 + c] * f;
    }
#pragma unroll
    for (int d = 1; d < 8; d <<= 1) {
        acc0 += __shfl_xor(acc0, d);
        acc1 += __shfl_xor(acc1, d);
        acc2 += __shfl_xor(acc2, d);
    }
    if (r == 0) {
        size_t ob = (size_t)lb * 3 * NPT + n;
        dst[ob]           = fmaxf(acc0, 0.0f);
        dst[ob + NPT]     = fmaxf(acc1, 0.0f);
        dst[ob + 2 * NPT] = fmaxf(acc2, 0.0f);
    }
}

extern "C" void kernel_launch(void* const* d_in, const int* in_sizes, int n_in,
                              void* d_out, int out_size, void* d_ws, size_t ws_size,
                              hipStream_t stream) {
    const float* x        = (const float*)d_in[0];
    const float* res      = (const float*)d_in[1];
    const float* outm     = (const float*)d_in[2];
    const float* w_mlp    = (const float*)d_in[3];
    const float* over_gen = (const float*)d_in[4];
    const float* coverage = (const float*)d_in[5];
    float* dst = (float*)d_out;

    const size_t keys_sz = (size_t)Bb * SORTN * sizeof(uint64_t);   // 2 MiB
    const size_t hist_sz = (size_t)Bb * NBUCK * sizeof(uint32_t);   // 16 KiB
    const size_t offs_sz = hist_sz;
    const size_t mort_sz = (size_t)Bb * NPT * sizeof(uint32_t);     // 256 KiB
    const size_t pord_sz = mort_sz;
    const size_t reor_sz = hist_sz + offs_sz + mort_sz + pord_sz;   // ~544 KiB
    const size_t maps_sz = (size_t)Bb * HWSZ * sizeof(float2);      // 8 MiB

    uint64_t* keys = (uint64_t*)d_ws;
    dim3 gU(SORTN / 256, Bb), gP(NPT / 256, Bb), gD(NPT * 8 / 256, Bb);

    if (ws_size >= keys_sz + reor_sz + maps_sz) {
        char* pbase = (char*)d_ws + keys_sz;
        uint32_t* hist   = (uint32_t*)pbase;
        uint32_t* offs   = (uint32_t*)(pbase + hist_sz);
        uint32_t* mort   = (uint32_t*)(pbase + hist_sz + offs_sz);
        uint32_t* porder = (uint32_t*)(pbase + hist_sz + offs_sz + mort_sz);
        float2*   maps   = (float2*)(pbase + reor_sz);
        dim3 gM(HWSZ / 256, Bb);
        build_maps<<<gM, 256, 0, stream>>>(res, outm, maps);
        uncert_keys_maps<<<gU, 256, 0, stream>>>(maps, over_gen, keys);
        run_sort_big(keys, Bb, stream);
        hipMemsetAsync(hist, 0, hist_sz, stream);
        hist_kernel<<<gP, 256, 0, stream>>>(keys, over_gen, coverage, hist, mort);
        scan_kernel<<<Bb, NBUCK, 0, stream>>>(hist, offs);
        scatter_kernel<<<gP, 256, 0, stream>>>(mort, offs, porder);
        render_kernel<<<gD, 256, 0, stream>>>(x, outm, w_mlp, over_gen, coverage,
                                              keys, porder, dst);
    } else if (ws_size >= keys_sz + reor_sz) {
        char* pbase = (char*)d_ws + keys_sz;
        uint32_t* hist   = (uint32_t*)pbase;
        uint32_t* offs   = (uint32_t*)(pbase + hist_sz);
        uint32_t* mort   = (uint32_t*)(pbase + hist_sz + offs_sz);
        uint32_t* porder = (uint32_t*)(pbase + hist_sz + offs_sz + mort_sz);
        uncert_keys_direct<<<gU, 256, 0, stream>>>(res, outm, over_gen, keys);
        run_sort_big(keys, Bb, stream);
        hipMemsetAsync(hist, 0, hist_sz, stream);
        hist_kernel<<<gP, 256, 0, stream>>>(keys, over_gen, coverage, hist, mort);
        scan_kernel<<<Bb, NBUCK, 0, stream>>>(hist, offs);
        scatter_kernel<<<gP, 256, 0, stream>>>(mort, offs, porder);
        render_kernel<<<gD, 256, 0, stream>>>(x, outm, w_mlp, over_gen, coverage,
                                              keys, porder, dst);
    } else {
        // minimal tier
        uncert_keys_direct<<<gU, 256, 0, stream>>>(res, outm, over_gen, keys);
        run_sort_big(keys, Bb, stream);
        render_kernel<<<gD, 256, 0, stream>>>(x, outm, w_mlp, over_gen, coverage,
                                              keys, (const uint32_t*)nullptr, dst);
    }
}